// Round 17
// baseline (1012.958 us; speedup 1.0000x reference)
//
#include <hip/hip_runtime.h>
#include <hip/hip_bf16.h>
#include <hip/hip_fp16.h>
#include <cstdint>

#define DD 20
#define HID 30
#define NB_SCAN 1024
#define HROW 32   // f16 hidden row stride in u16 units (64 B, one cacheline)

typedef unsigned int  u32;
typedef unsigned short u16;
typedef _Float16 hf2 __attribute__((ext_vector_type(2)));

__device__ __forceinline__ hf2 as_hf2(u32 u){ union{u32 u; hf2 v;} c; c.u=u; return c.v; }
__device__ __forceinline__ u32 pkhf(float a, float b){
  union{hf2 v; u32 u;} c; c.v[0]=(_Float16)a; c.v[1]=(_Float16)b; return c.u;
}
__device__ __forceinline__ float lo16f(u32 u){ union{u16 s; _Float16 h;} c; c.s=(u16)(u&0xFFFF); return (float)c.h; }
__device__ __forceinline__ float hi16f(u32 u){ union{u16 s; _Float16 h;} c; c.s=(u16)(u>>16); return (float)c.h; }

__device__ __forceinline__ float dot10p(const u32* hh, const u32* __restrict__ w, float acc){
#if __has_builtin(__builtin_amdgcn_fdot2)
#pragma unroll
  for (int c=0;c<10;c++) acc = __builtin_amdgcn_fdot2(as_hf2(hh[c]), as_hf2(w[c]), acc, false);
#else
#pragma unroll
  for (int c=0;c<10;c++) acc += lo16f(hh[c])*lo16f(w[c]) + hi16f(hh[c])*hi16f(w[c]);
#endif
  return acc;
}

__device__ __forceinline__ void load20(const float* __restrict__ p, float* r){
  const float4* q = (const float4*)p;
#pragma unroll
  for (int i=0;i<5;i++){ float4 v=q[i]; r[4*i+0]=v.x; r[4*i+1]=v.y; r[4*i+2]=v.z; r[4*i+3]=v.w; }
}

__device__ __forceinline__ u32 pkbf(float a, float b){
  u32 ua=__float_as_uint(a); ua=(ua+0x7FFFu+((ua>>16)&1u))>>16;
  u32 ub=__float_as_uint(b); ub=(ub+0x7FFFu+((ub>>16)&1u))>>16;
  return ua | (ub<<16);
}

__global__ void k_prep(const float* __restrict__ rela, const float* __restrict__ w1,
                       const float* __restrict__ wp, const float* __restrict__ wn,
                       const float* __restrict__ wf,
                       float* __restrict__ W3, float* __restrict__ AR, float* __restrict__ AQ,
                       int nrel){
  int t = blockIdx.x*blockDim.x + threadIdx.x;
  if (t < 3*DD*DD){
    int s = t/(DD*DD), idx = t%(DD*DD);
    W3[t] = (s==0)?wp[idx]:((s==1)?wn[idx]:wf[idx]);
  }
  if (t < nrel*HID){
    int r=t/HID, j=t-r*HID;
    float sr=0.f, sq=0.f;
#pragma unroll
    for (int k=0;k<DD;k++){
      float e = rela[r*DD+k];
      sr += e*w1[j*3*DD + DD + k];
      sq += e*w1[j*3*DD + 2*DD + k];
    }
    AR[r*32+j]=sr; AQ[r*32+j]=sq;
  }
}

__global__ void k_rwtw(const float* __restrict__ rela, const float* __restrict__ timee,
                       const float* __restrict__ W3,
                       float* __restrict__ RW, float* __restrict__ TW,
                       int nrel, int ntime){
  int t = blockIdx.x*blockDim.x+threadIdx.x;
  int totR = 3*nrel*DD, totT = 3*ntime*DD;
  if (t < totR){
    int sel = t/(nrel*DD); int rem = t - sel*nrel*DD; int r = rem/DD; int i = rem - r*DD;
    const float* w = W3 + sel*DD*DD + i*DD;
    const float* e = rela + (size_t)r*DD;
    float s=0.f;
#pragma unroll
    for (int k=0;k<DD;k++) s += e[k]*w[k];
    RW[t]=s;
  }
  if (t < totT){
    int sel = t/(ntime*DD); int rem = t - sel*ntime*DD; int tt = rem/DD; int i = rem - tt*DD;
    const float* w = W3 + sel*DD*DD + i*DD;
    const float* e = timee + (size_t)tt*DD;
    float s=0.f;
#pragma unroll
    for (int k=0;k<DD;k++) s += e[k]*w[k];
    TW[t]=s;
  }
}

// f32 RT (fallback path only)
__global__ void k_rt(const float* __restrict__ rela, const float* __restrict__ timee,
                     const float* __restrict__ W3, float* __restrict__ RT,
                     int nrel, int ntime){
  int row = blockIdx.x*blockDim.x+threadIdx.x;
  int tot = 3*nrel*ntime;
  if (row>=tot) return;
  int per = nrel*ntime;
  int sel = row/per; int rem = row - sel*per; int r = rem/ntime; int t = rem - r*ntime;
  float e[DD], tv[DD];
  load20(rela + (size_t)r*DD, e);
  load20(timee + (size_t)t*DD, tv);
#pragma unroll
  for (int k=0;k<DD;k++) e[k]+=tv[k];
  const float* W = W3 + sel*DD*DD;
  float o[DD];
#pragma unroll
  for (int i=0;i<DD;i++){
    const float4* wr = (const float4*)(W + i*DD);
    float s=0.f;
#pragma unroll
    for (int c=0;c<5;c++){ float4 w=wr[c]; s += e[4*c]*w.x + e[4*c+1]*w.y + e[4*c+2]*w.z + e[4*c+3]*w.w; }
    o[i]=s;
  }
  float4* op=(float4*)(RT + (size_t)row*DD);
#pragma unroll
  for (int c=0;c<5;c++){ float4 v; v.x=o[4*c]; v.y=o[4*c+1]; v.z=o[4*c+2]; v.w=o[4*c+3]; op[c]=v; }
}

// ---- F0: zero d_out/bufF (even blocks) || hist layers 0+1 (odd) ----
__global__ void __launch_bounds__(256) k_pre(const int* __restrict__ dst, int* __restrict__ cnt,
        int* __restrict__ rank, int E, int N,
        float4* __restrict__ dout4, size_t nd4,
        float4* __restrict__ bF, size_t nf4){
  int g=blockIdx.x, tid=threadIdx.x;
  int half=gridDim.x>>1;
  if (g & 1){
    int stride=half*256;
    int E2=2*E;
    for (int e=(g>>1)*256+tid; e<E2; e+=stride){
      int l=(e>=E)?1:0;
      rank[e]=atomicAdd(&cnt[(size_t)l*N+dst[e]],1);
    }
  } else {
    float4 z=make_float4(0.f,0.f,0.f,0.f);
    size_t i=(size_t)(g>>1)*256+tid, st=(size_t)half*256;
    for (size_t k=i;k<nd4;k+=st) dout4[k]=z;
    for (size_t k=i;k<nf4;k+=st) bF[k]=z;
  }
}

// ---- scans (M elements), exclusive; scan_write adds `base` and handles deg-0 rows ----
__global__ void k_scan_part(const int* __restrict__ cnt, int* __restrict__ part, int M, int C){
  __shared__ int sm[256];
  int b=blockIdx.x, t=threadIdx.x;
  int lo=b*C, hi=lo+C; if (hi>M) hi=M; if (lo>M) lo=M;
  int s=0;
  for (int i=lo+t; i<hi; i+=256) s+=cnt[i];
  sm[t]=s; __syncthreads();
  for (int o=128;o>0;o>>=1){ if (t<o) sm[t]+=sm[t+o]; __syncthreads(); }
  if (t==0) part[b]=sm[0];
}

__global__ void k_scan_top(int* __restrict__ part, int* __restrict__ listc){
  __shared__ int sm[NB_SCAN];
  int t=threadIdx.x;
  if (t==0){ listc[0]=0; listc[1]=0; listc[2]=0; listc[3]=0; }
  int v=part[t]; sm[t]=v; __syncthreads();
  for (int o=1;o<NB_SCAN;o<<=1){
    int u=(t>=o)?sm[t-o]:0; __syncthreads();
    sm[t]+=u; __syncthreads();
  }
  part[t]=sm[t]-v;   // exclusive
}

// ZM=1: zero f16 rows of zb0 (i<Nsplit) / zb1 (i>=Nsplit) when cnt==0.
// ZM=2: write bcls into d_out slot of node i when cnt==0 (deg-0 final nodes).
template<int ZM>
__global__ void k_scan_write(const int* __restrict__ cnt, const int* __restrict__ part,
                             int* __restrict__ rowptr, int M, int C, int base,
                             u16* __restrict__ zb0, u16* __restrict__ zb1, int Nsplit,
                             const int* __restrict__ nb, const int* __restrict__ ne,
                             const int* __restrict__ nentp, const float* __restrict__ bcls,
                             float* __restrict__ dout){
  __shared__ int sm[256];
  int b=blockIdx.x, t=threadIdx.x;
  int lo=b*C, hi=lo+C; if (hi>M) hi=M; if (lo>M) lo=M;
  int run=part[b]+base;
  for (int bb=lo; bb<hi; bb+=256){
    int i=bb+t;
    int v=(i<hi)?cnt[i]:0;
    if (i<hi && v==0){
      if (ZM==1){
        u16* o=(i<Nsplit)? zb0+(size_t)i*HROW : zb1+(size_t)(i-Nsplit)*HROW;
        uint4 z=make_uint4(0u,0u,0u,0u);
        uint4* o4=(uint4*)o;
        o4[0]=z; o4[1]=z; *((uint2*)(o4+2))=make_uint2(0u,0u);
      } else if (ZM==2){
        long long stride=nentp[0];
        dout[(long long)nb[i]*stride + ne[i]] = bcls[0];
      }
    }
    sm[t]=v; __syncthreads();
    for (int o=1;o<256;o<<=1){
      int u=(t>=o)?sm[t-o]:0; __syncthreads();
      sm[t]+=u; __syncthreads();
    }
    if (i<hi) rowptr[i]=run+sm[t]-v;
    int tot=sm[255];
    __syncthreads();
    run+=tot;
  }
  if (hi==M && t==0) rowptr[M]=run;
}

// ---- scatter layers 0+1 together (global CSR positions) ----
__global__ void __launch_bounds__(256) k_scat01(const int* __restrict__ src,const int* __restrict__ dst,
  const int* __restrict__ rel,const int* __restrict__ qrel,const int* __restrict__ rtm,
  const int* __restrict__ rank,const int* __restrict__ rowptr,int4* __restrict__ recs,int E,int N){
  int e=blockIdx.x*blockDim.x+threadIdx.x;
  if (e>=2*E) return;
  int l=(e>=E)?1:0;
  int d=dst[e];
  int pos=rowptr[(size_t)l*N+d]+rank[e];
  recs[pos]=make_int4(src[e], rel[e]|(qrel[e]<<16), rtm[e], d);
}

// ---- fused layer: f16 hidden (leaky pre-applied, 64B rows, packed dots), streamed z,
//      RW/TW transform, bf16-packed LDS segmented reduce.
//      RMODE=1: odd blocks do next-next-layer hist (1/2 share).
//      RMODE=2: every 3rd block does next-layer scat (1/3 share).
//      FINAL: head writes bcls+leakydot directly to d_out; crossings -> bufF + list. ----
template<bool HASH,bool FINAL,int RMODE>
__global__ void __launch_bounds__(256) k_fused(
    const int4* __restrict__ recs,
    const u16* __restrict__ hin, u16* __restrict__ hout, float* __restrict__ bufF,
    const float* __restrict__ RW, const float* __restrict__ TW,
    const float* __restrict__ AR, const float* __restrict__ AQ,
    const float* __restrict__ w1, const float* __restrict__ w2, const float* __restrict__ W3,
    int E, int nrel, int ntime,
    const int* __restrict__ hB_dst, int* __restrict__ hB_cnt, int* __restrict__ hB_rank, int hB_E,
    const int* __restrict__ sA_src, const int* __restrict__ sA_dst,
    const int* __restrict__ sA_rel, const int* __restrict__ sA_qrel,
    const int* __restrict__ sA_rtm, const int* __restrict__ sA_rank,
    const int* __restrict__ sA_rowptr, int4* __restrict__ sA_recs, int sA_E,
    const float* __restrict__ wcls, const float* __restrict__ bcls,
    const int* __restrict__ nbv, const int* __restrict__ nev, const int* __restrict__ nentp,
    float* __restrict__ outp,
    int* __restrict__ list, int* __restrict__ listc)
{
  int lb;
  if (RMODE==1){
    int g=blockIdx.x;
    if (g & 1){                               // hist role, 1/2 of blocks
      int H=gridDim.x>>1;
      int stride=H*256;
      for (int e=(g>>1)*256+threadIdx.x; e<hB_E; e+=stride)
        hB_rank[e]=atomicAdd(&hB_cnt[hB_dst[e]],1);
      return;
    }
    lb=g>>1;
  } else if (RMODE==2){
    int g=blockIdx.x;
    int r3=g%3, b3=g/3;
    if (r3==2){                               // scat role, 1/3 of blocks
      int H=gridDim.x/3;
      int stride=H*256;
      for (int e=b3*256+threadIdx.x; e<sA_E; e+=stride){
        int d=sA_dst[e];
        int pos=sA_rowptr[d]+sA_rank[e];
        sA_recs[pos]=make_int4(sA_src[e], sA_rel[e]|(sA_qrel[e]<<16), sA_rtm[e], d);
      }
      return;
    }
    lb=b3*2+r3;
  } else lb=blockIdx.x;
  int bstart=lb*256;
  if (bstart>=E) return;

  __shared__ u32   sW1hp[HID*10];
  __shared__ u32   sW3p[3*DD*10];
  __shared__ float sW2[32];
  __shared__ u32   smsg[256*10];
  __shared__ int   sdst[256];
  __shared__ int   s_prevdst, s_nextdst;
  if (HASH){
    for (int t=threadIdx.x; t<HID*10; t+=blockDim.x){
      int j=t/10, c=t-j*10;
      sW1hp[t]=pkhf(w1[j*3*DD+2*c], w1[j*3*DD+2*c+1]);
    }
    for (int t=threadIdx.x; t<3*DD*10; t+=blockDim.x){
      int i=t/10, c=t-i*10;
      sW3p[t]=pkhf(W3[i*DD+2*c], W3[i*DD+2*c+1]);
    }
  }
  if (threadIdx.x<HID) sW2[threadIdx.x]=w2[threadIdx.x];

  int tid = threadIdx.x;
  int bsize = E - bstart; if (bsize>256) bsize=256;
  int j = bstart + tid;
  bool active = (tid < bsize);

  if (tid==0){
    s_prevdst = (bstart>0) ? recs[-1 + (ptrdiff_t)bstart].w : -1;
    s_nextdst = (bstart+bsize < E) ? recs[bstart+bsize].w : -1;
  }
  __syncthreads();

  int dstv = -1;
  float m[DD];
  if (active){
    int4 rc = recs[j];
    int s = rc.x;
    int r = rc.y & 0xFFFF;
    int q = ((unsigned)rc.y) >> 16;
    int t = rc.z;
    dstv  = rc.w;
    int sel = (t>0)?2:((t==0)?1:0);
    int ta = (t<0)?-t:t;

    u32 hh[10];
    if (HASH){
      const uint4* hp=(const uint4*)(hin+(size_t)s*HROW);
      uint4 A=hp[0], B=hp[1]; uint2 Cc=*((const uint2*)(hp+2));
      hh[0]=A.x; hh[1]=A.y; hh[2]=A.z; hh[3]=A.w;
      hh[4]=B.x; hh[5]=B.y; hh[6]=B.z; hh[7]=B.w;
      hh[8]=Cc.x; hh[9]=Cc.y;
    }

    float z=0.f;
    {
      const float4* ap=(const float4*)(AR+(size_t)r*32);
      const float4* qp=(const float4*)(AQ+(size_t)q*32);
#pragma unroll
      for (int c=0;c<7;c++){
        float4 x=ap[c], y=qp[c];
        float s4[4]={x.x+y.x, x.y+y.y, x.z+y.z, x.w+y.w};
#pragma unroll
        for (int u=0;u<4;u++){
          int jj=4*c+u;
          float sum=s4[u];
          if (HASH) sum = dot10p(hh, &sW1hp[jj*10], sum);
          z += fmaxf(sum,0.f)*sW2[jj];
        }
      }
      float2 x2=*(const float2*)(AR+(size_t)r*32+28);
      float2 y2=*(const float2*)(AQ+(size_t)q*32+28);
      float s0=x2.x+y2.x, s1=x2.y+y2.y;
      if (HASH){
        s0 = dot10p(hh, &sW1hp[28*10], s0);
        s1 = dot10p(hh, &sW1hp[29*10], s1);
      }
      z += fmaxf(s0,0.f)*sW2[28] + fmaxf(s1,0.f)*sW2[29];
    }
    float score = 1.f/(1.f+__expf(-z));

    const float4* rwp=(const float4*)(RW + ((size_t)(sel*nrel+r))*DD);
    const float4* twp=(const float4*)(TW + ((size_t)(sel*ntime+ta))*DD);
#pragma unroll
    for (int c=0;c<5;c++){
      float4 a4=rwp[c], b4=twp[c];
      float mv[4]={a4.x+b4.x, a4.y+b4.y, a4.z+b4.z, a4.w+b4.w};
      if (HASH){
#pragma unroll
        for (int u=0;u<4;u++)
          mv[u] = dot10p(hh, &sW3p[(sel*DD+4*c+u)*10], mv[u]);
      }
#pragma unroll
      for (int u=0;u<4;u++) m[4*c+u]=score*mv[u];
      smsg[tid*10+2*c]  =pkbf(m[4*c+0],m[4*c+1]);
      smsg[tid*10+2*c+1]=pkbf(m[4*c+2],m[4*c+3]);
    }
  }
  sdst[tid] = active ? dstv : -2;
  __syncthreads();

  if (!active) return;
  bool isHead = (tid==0) ? (s_prevdst != dstv) : (sdst[tid-1] != dstv);
  if (!(isHead || tid==0)) return;
  int k=tid+1;
  for (; k<bsize && sdst[k]==dstv; ++k){
    const u32* row=&smsg[k*10];
#pragma unroll
    for (int i2=0;i2<10;i2++){
      u32 w=row[i2];
      m[2*i2]  +=__uint_as_float(w<<16);
      m[2*i2+1]+=__uint_as_float(w&0xFFFF0000u);
    }
  }
  bool crossStart = (tid==0 && !isHead);
  bool crossEnd   = (k==bsize) && (s_nextdst==dstv);
  if (crossStart || crossEnd){
    float* o = bufF + (size_t)dstv*DD;
#pragma unroll
    for (int i=0;i<DD;i++) atomicAdd(o+i, m[i]);
    if (isHead){
      int p = atomicAdd(listc,1);
      list[p] = dstv;
    }
  } else {
    if (!FINAL){
      u32 o10[10];
#pragma unroll
      for (int i2=0;i2<10;i2++){
        float x0=m[2*i2], x1=m[2*i2+1];
        x0=fmaxf(x0,0.01f*x0); x1=fmaxf(x1,0.01f*x1);
        o10[i2]=pkhf(x0,x1);
      }
      uint4* hp=(uint4*)(hout+(size_t)dstv*HROW);
      hp[0]=make_uint4(o10[0],o10[1],o10[2],o10[3]);
      hp[1]=make_uint4(o10[4],o10[5],o10[6],o10[7]);
      *((uint2*)(hp+2))=make_uint2(o10[8],o10[9]);
    } else {
      float rsum=bcls[0];
#pragma unroll
      for (int i=0;i<DD;i++){ float x=fmaxf(m[i],0.01f*m[i]); rsum += x*wcls[i]; }
      long long stride = nentp[0];
      outp[(long long)nbv[dstv]*stride + nev[dstv]] = rsum;
    }
  }
}

// ---- finish crossing segments: FINAL -> d_out (bcls + leakydot); else f16 hout + re-zero ----
template<bool FINAL>
__global__ void __launch_bounds__(256) k_fixup(float* __restrict__ bufF, u16* __restrict__ hout,
   const float* __restrict__ wcls, const float* __restrict__ bcls,
   const int* __restrict__ nb, const int* __restrict__ ne, const int* __restrict__ nentp,
   float* __restrict__ out,
   const int* __restrict__ list, const int* __restrict__ listc){
  int c=*listc;
  for (int i=blockIdx.x*blockDim.x+threadIdx.x; i<c; i+=gridDim.x*blockDim.x){
    int n=list[i];
    float* p=bufF+(size_t)n*DD;
    if (FINAL){
      float rsum=bcls[0];
#pragma unroll
      for (int jj=0;jj<DD;jj++){ float v=p[jj]; float x=fmaxf(v,0.01f*v); rsum+=x*wcls[jj]; }
      long long stride=nentp[0];
      out[(long long)nb[n]*stride+ne[n]]=rsum;
    } else {
      float v[DD];
#pragma unroll
      for (int jj=0;jj<DD;jj++){ v[jj]=p[jj]; p[jj]=0.f; }
      u32 o10[10];
#pragma unroll
      for (int i2=0;i2<10;i2++){
        float x0=v[2*i2], x1=v[2*i2+1];
        x0=fmaxf(x0,0.01f*x0); x1=fmaxf(x1,0.01f*x1);
        o10[i2]=pkhf(x0,x1);
      }
      uint4* hp=(uint4*)(hout+(size_t)n*HROW);
      hp[0]=make_uint4(o10[0],o10[1],o10[2],o10[3]);
      hp[1]=make_uint4(o10[4],o10[5],o10[6],o10[7]);
      *((uint2*)(hp+2))=make_uint2(o10[8],o10[9]);
    }
  }
}

// ================= fallback (round-2 proven atomic path, f32) =================
template<bool HASH>
__global__ void __launch_bounds__(256) k_edge(
    const int* __restrict__ src, const int* __restrict__ dst,
    const int* __restrict__ rel, const int* __restrict__ qrel,
    const int* __restrict__ rtm,
    const float* __restrict__ hin, float* __restrict__ hout,
    const float* __restrict__ RT, const float* __restrict__ AR, const float* __restrict__ AQ,
    const float* __restrict__ w1, const float* __restrict__ w2, const float* __restrict__ W3,
    int E, int nrel, int ntime)
{
  __shared__ float sW1h[HID*DD];
  __shared__ float sW2[32];
  __shared__ float sW3[3*DD*DD];
  for (int t=threadIdx.x; t<HID*DD; t+=blockDim.x){ int j=t/DD,k=t-j*DD; sW1h[t]=w1[j*3*DD+k]; }
  if (threadIdx.x<HID) sW2[threadIdx.x]=w2[threadIdx.x];
  for (int t=threadIdx.x; t<3*DD*DD; t+=blockDim.x) sW3[t]=W3[t];
  __syncthreads();
  int e = blockIdx.x*blockDim.x+threadIdx.x;
  if (e>=E) return;
  int s=src[e], d=dst[e], r=rel[e], q=qrel[e], t=rtm[e];
  int sel = (t>0)?2:((t==0)?1:0);
  int ta = (t<0)?-t:t;
  float h[DD];
  if (HASH){
    load20(hin+(size_t)s*DD, h);
#pragma unroll
    for (int i=0;i<DD;i++) h[i]=fmaxf(h[i],0.01f*h[i]);
  }
  float a[HID];
  {
    const float4* ap=(const float4*)(AR+(size_t)r*32);
    const float4* qp=(const float4*)(AQ+(size_t)q*32);
#pragma unroll
    for (int c=0;c<7;c++){
      float4 x=ap[c], y=qp[c];
      a[4*c+0]=x.x+y.x; a[4*c+1]=x.y+y.y; a[4*c+2]=x.z+y.z; a[4*c+3]=x.w+y.w;
    }
    float2 x=*(const float2*)(AR+(size_t)r*32+28);
    float2 y=*(const float2*)(AQ+(size_t)q*32+28);
    a[28]=x.x+y.x; a[29]=x.y+y.y;
  }
  if (HASH){
#pragma unroll
    for (int j=0;j<HID;j++){
      const float4* wr=(const float4*)&sW1h[j*DD];
      float sum=a[j];
#pragma unroll
      for (int c=0;c<5;c++){ float4 w=wr[c]; sum += h[4*c]*w.x+h[4*c+1]*w.y+h[4*c+2]*w.z+h[4*c+3]*w.w; }
      a[j]=sum;
    }
  }
  float z=0.f;
#pragma unroll
  for (int j=0;j<HID;j++) z += fmaxf(a[j],0.f)*sW2[j];
  float score = 1.f/(1.f+__expf(-z));
  float tr[DD];
  load20(RT + ((size_t)(sel*nrel+r)*ntime + ta)*DD, tr);
  if (HASH){
    const float* Ws = sW3 + sel*DD*DD;
#pragma unroll
    for (int i=0;i<DD;i++){
      const float4* wr=(const float4*)(Ws+i*DD);
      float sum=tr[i];
#pragma unroll
      for (int c=0;c<5;c++){ float4 w=wr[c]; sum += h[4*c]*w.x+h[4*c+1]*w.y+h[4*c+2]*w.z+h[4*c+3]*w.w; }
      tr[i]=sum;
    }
  }
  float* o = hout + (size_t)d*DD;
#pragma unroll
  for (int i=0;i<DD;i++) atomicAdd(o+i, score*tr[i]);
}

__global__ void k_result(const float* __restrict__ h, const float* __restrict__ wcls,
                         const float* __restrict__ bcls, float* __restrict__ res, int N){
  int i = blockIdx.x*blockDim.x+threadIdx.x;
  if (i>=N) return;
  float acc = bcls[0];
  const float4* q=(const float4*)(h+(size_t)i*DD);
#pragma unroll
  for (int c=0;c<5;c++){
    float4 v=q[c];
    float x0=fmaxf(v.x,0.01f*v.x), x1=fmaxf(v.y,0.01f*v.y);
    float x2=fmaxf(v.z,0.01f*v.z), x3=fmaxf(v.w,0.01f*v.w);
    acc += x0*wcls[4*c]+x1*wcls[4*c+1]+x2*wcls[4*c+2]+x3*wcls[4*c+3];
  }
  res[i]=acc;
}

__global__ void k_scatter(const float* __restrict__ res, const int* __restrict__ nb,
                          const int* __restrict__ ne, const int* __restrict__ nentp,
                          float* __restrict__ out, int N){
  int i=blockIdx.x*blockDim.x+threadIdx.x;
  if (i>=N) return;
  long long stride = nentp[0];
  out[(long long)nb[i]*stride + ne[i]] = res[i];
}

extern "C" void kernel_launch(void* const* d_in, const int* in_sizes, int n_in,
                              void* d_out, int out_size, void* d_ws, size_t ws_size,
                              hipStream_t stream){
  const int*   src =(const int*)d_in[0];
  const int*   dst =(const int*)d_in[1];
  const int*   rel =(const int*)d_in[2];
  const int*   qrel=(const int*)d_in[3];
  const int*   rtm =(const int*)d_in[4];
  const int*   nb  =(const int*)d_in[5];
  const int*   ne  =(const int*)d_in[6];
  const float* rela=(const float*)d_in[7];
  const float* timee=(const float*)d_in[8];
  const float* w1  =(const float*)d_in[9];
  const float* w2  =(const float*)d_in[10];
  const float* wp  =(const float*)d_in[11];
  const float* wn  =(const float*)d_in[12];
  const float* wf  =(const float*)d_in[13];
  const float* wcls=(const float*)d_in[14];
  const float* bcls=(const float*)d_in[15];
  const int*   nentp=(const int*)d_in[17];

  const int Lc=3;
  int LE=in_sizes[0]; int E=LE/Lc;
  int N=in_sizes[5];
  int nrel=in_sizes[7]/DD;
  int ntime=in_sizes[8]/DD;

  auto al=[](size_t x){ return (x+(size_t)255)&~(size_t)255; };
  size_t szBufH=al((size_t)N*HROW*2);
  size_t szBuf =al((size_t)N*DD*4);
  size_t szRW  =al((size_t)3*nrel*DD*4);
  size_t szTW  =al((size_t)3*ntime*DD*4);
  size_t szRTf =al((size_t)3*nrel*ntime*DD*4);
  size_t szA   =al((size_t)nrel*32*4);
  size_t szW3  =al((size_t)3*DD*DD*4);
  size_t szRow =al(((size_t)3*N+3)*4);
  size_t szRank=al((size_t)LE*4);
  size_t szCnt =al((size_t)Lc*N*4);
  size_t szRecs=al((size_t)LE*16);
  size_t szPart=al((size_t)NB_SCAN*4);
  size_t szList=al((size_t)(131072+16)*4);
  size_t need = 2*szBufH+szBuf+szRW+szTW+2*szA+szW3+szRow+szRank+szCnt+szRecs+szPart+szList;

  dim3 blk(256);
  int prepTot = (3*DD*DD > nrel*HID) ? 3*DD*DD : nrel*HID;
  int rtTot=3*nrel*ntime;
  int rwtwTot = 3*ntime*DD;

  if (ws_size >= need){
    char* base=(char*)d_ws;
    size_t off=0;
    u16*   b0 =(u16*)(base+off);    off+=szBufH;
    u16*   b1 =(u16*)(base+off);    off+=szBufH;
    float* bufF=(float*)(base+off); off+=szBuf;
    float* RW  =(float*)(base+off); off+=szRW;
    float* TW  =(float*)(base+off); off+=szTW;
    float* AR  =(float*)(base+off); off+=szA;
    float* AQ  =(float*)(base+off); off+=szA;
    float* W3  =(float*)(base+off); off+=szW3;
    int*   rowptr=(int*)(base+off); off+=szRow;
    int*   rowptr2=rowptr+(size_t)2*N+1;
    int*   rank=(int*)(base+off);  off+=szRank;
    int*   cnt =(int*)(base+off);  off+=szCnt;
    int4*  recs=(int4*)(base+off); off+=szRecs;
    int*   part=(int*)(base+off);  off+=szPart;
    int*   listc=(int*)(base+off);
    int*   list =listc+16;          off+=szList;

    float* dout=(float*)d_out;

    (void)hipMemsetAsync(cnt,0,(size_t)Lc*N*4,stream);
    k_prep<<<dim3((prepTot+255)/256),blk,0,stream>>>(rela,w1,wp,wn,wf,W3,AR,AQ,nrel);
    k_rwtw<<<dim3((rwtwTot+255)/256),blk,0,stream>>>(rela,timee,W3,RW,TW,nrel,ntime);

    size_t nd4=(size_t)out_size>>2;
    size_t nb4=(size_t)N*DD/4;
    k_pre<<<dim3(8192),blk,0,stream>>>(dst,cnt,rank,E,N,(float4*)dout,nd4,
                                       (float4*)bufF,nb4);

    int LB=(E+255)/256;
    int H=(LB+1)/2;

    // scan layers 0+1 over 2N (zero deg-0 rows of b0/b1; resets listc[0..3])
    {
      int M=2*N, C=(M+NB_SCAN-1)/NB_SCAN;
      k_scan_part<<<dim3(NB_SCAN),blk,0,stream>>>(cnt,part,M,C);
      k_scan_top<<<dim3(1),dim3(NB_SCAN),0,stream>>>(part,listc);
      k_scan_write<1><<<dim3(NB_SCAN),blk,0,stream>>>(cnt,part,rowptr,M,C,0,
          b0,b1,N, nullptr,nullptr,nullptr,nullptr,nullptr);
    }
    k_scat01<<<dim3((2*E+255)/256),blk,0,stream>>>(src,dst,rel,qrel,rtm,rank,rowptr,recs,E,N);

    // fused layer 0 (no hidden): compute || hist(l2) at 1/2 share; lists into slot 0
    k_fused<false,false,1><<<dim3(2*LB),blk,0,stream>>>(recs,nullptr,b0,bufF,
        RW,TW,AR,AQ,w1,w2,W3,E,nrel,ntime,
        dst+(size_t)2*E,cnt+(size_t)2*N,rank+(size_t)2*E,E,
        nullptr,nullptr,nullptr,nullptr,nullptr,nullptr,nullptr,nullptr,0,
        wcls,bcls,nb,ne,nentp,dout,
        list,listc);
    k_fixup<false><<<dim3(128),blk,0,stream>>>(bufF,b0,wcls,bcls,nb,ne,nentp,dout,list,listc);

    // scan layer 2 (base 2E; deg-0 nodes get bcls written to d_out; resets listc[0..3])
    {
      int C=(N+NB_SCAN-1)/NB_SCAN;
      k_scan_part<<<dim3(NB_SCAN),blk,0,stream>>>(cnt+(size_t)2*N,part,N,C);
      k_scan_top<<<dim3(1),dim3(NB_SCAN),0,stream>>>(part,listc);
      k_scan_write<2><<<dim3(NB_SCAN),blk,0,stream>>>(cnt+(size_t)2*N,part,rowptr2,N,C,2*E,
          nullptr,nullptr,0, nb,ne,nentp,bcls,dout);
    }

    // fused layer 1: compute || scat(l2) at 1/3 share; lists into slot 1
    k_fused<true,false,2><<<dim3(3*H),blk,0,stream>>>(recs+(size_t)E,b0,b1,bufF,
        RW,TW,AR,AQ,w1,w2,W3,E,nrel,ntime,
        nullptr,nullptr,nullptr,0,
        src+(size_t)2*E,dst+(size_t)2*E,rel+(size_t)2*E,qrel+(size_t)2*E,rtm+(size_t)2*E,
        rank+(size_t)2*E,rowptr2,recs,E,
        wcls,bcls,nb,ne,nentp,dout,
        list+32768,listc+1);
    k_fixup<false><<<dim3(128),blk,0,stream>>>(bufF,b1,wcls,bcls,nb,ne,nentp,dout,list+32768,listc+1);

    // fused layer 2 (FINAL): heads write d_out directly; crossings -> bufF + slot 2
    k_fused<true,true,0><<<dim3(LB),blk,0,stream>>>(recs+(size_t)2*E,b1,nullptr,bufF,
        RW,TW,AR,AQ,w1,w2,W3,E,nrel,ntime,
        nullptr,nullptr,nullptr,0,
        nullptr,nullptr,nullptr,nullptr,nullptr,nullptr,nullptr,nullptr,0,
        wcls,bcls,nb,ne,nentp,dout,
        list+65536,listc+2);
    k_fixup<true><<<dim3(128),blk,0,stream>>>(bufF,nullptr,wcls,bcls,nb,ne,nentp,dout,list+65536,listc+2);
  } else {
    // fallback: proven round-2 atomic path (scratch carved from d_out, res in ws)
    char* base=(char*)d_out; float* res=(float*)d_ws;
    size_t off=0;
    float* buf0=(float*)(base+off); off+=szBuf;
    float* buf1=(float*)(base+off); off+=szBuf;
    float* RT  =(float*)(base+off); off+=szRTf;
    float* AR  =(float*)(base+off); off+=szA;
    float* AQ  =(float*)(base+off); off+=szA;
    float* W3  =(float*)(base+off); off+=szW3;
    k_prep<<<dim3((prepTot+255)/256),blk,0,stream>>>(rela,w1,wp,wn,wf,W3,AR,AQ,nrel);
    k_rt<<<dim3((rtTot+255)/256),blk,0,stream>>>(rela,timee,W3,RT,nrel,ntime);
    dim3 egrid((E+255)/256);
    dim3 ngrid((N+255)/256);
    (void)hipMemsetAsync(buf0,0,(size_t)N*DD*4,stream);
    k_edge<false><<<egrid,blk,0,stream>>>(src,dst,rel,qrel,rtm,nullptr,buf0,RT,AR,AQ,w1,w2,W3,E,nrel,ntime);
    (void)hipMemsetAsync(buf1,0,(size_t)N*DD*4,stream);
    k_edge<true><<<egrid,blk,0,stream>>>(src+(size_t)E,dst+(size_t)E,rel+(size_t)E,qrel+(size_t)E,rtm+(size_t)E,
                                         buf0,buf1,RT,AR,AQ,w1,w2,W3,E,nrel,ntime);
    (void)hipMemsetAsync(buf0,0,(size_t)N*DD*4,stream);
    k_edge<true><<<egrid,blk,0,stream>>>(src+(size_t)2*E,dst+(size_t)2*E,rel+(size_t)2*E,qrel+(size_t)2*E,rtm+(size_t)2*E,
                                         buf1,buf0,RT,AR,AQ,w1,w2,W3,E,nrel,ntime);
    k_result<<<ngrid,blk,0,stream>>>(buf0,wcls,bcls,res,N);
    (void)hipMemsetAsync(d_out,0,(size_t)out_size*sizeof(float),stream);
    k_scatter<<<ngrid,blk,0,stream>>>(res,nb,ne,nentp,(float*)d_out,N);
  }
}

// Round 18
// 960.111 us; speedup vs baseline: 1.0550x; 1.0550x over previous
//
#include <hip/hip_runtime.h>
#include <hip/hip_bf16.h>
#include <hip/hip_fp16.h>
#include <cstdint>

#define DD 20
#define HID 30
#define NB_SCAN 1024
#define HROW 32   // f16 hidden row stride in u16 units (64 B, one cacheline)

typedef unsigned int  u32;
typedef unsigned short u16;
typedef _Float16 hf2 __attribute__((ext_vector_type(2)));

__device__ __forceinline__ hf2 as_hf2(u32 u){ union{u32 u; hf2 v;} c; c.u=u; return c.v; }
__device__ __forceinline__ u32 pkhf(float a, float b){
  union{hf2 v; u32 u;} c; c.v[0]=(_Float16)a; c.v[1]=(_Float16)b; return c.u;
}
__device__ __forceinline__ float lo16f(u32 u){ union{u16 s; _Float16 h;} c; c.s=(u16)(u&0xFFFF); return (float)c.h; }
__device__ __forceinline__ float hi16f(u32 u){ union{u16 s; _Float16 h;} c; c.s=(u16)(u>>16); return (float)c.h; }

__device__ __forceinline__ float dot10p(const u32* hh, const u32* __restrict__ w, float acc){
#if __has_builtin(__builtin_amdgcn_fdot2)
#pragma unroll
  for (int c=0;c<10;c++) acc = __builtin_amdgcn_fdot2(as_hf2(hh[c]), as_hf2(w[c]), acc, false);
#else
#pragma unroll
  for (int c=0;c<10;c++) acc += lo16f(hh[c])*lo16f(w[c]) + hi16f(hh[c])*hi16f(w[c]);
#endif
  return acc;
}

__device__ __forceinline__ void load20(const float* __restrict__ p, float* r){
  const float4* q = (const float4*)p;
#pragma unroll
  for (int i=0;i<5;i++){ float4 v=q[i]; r[4*i+0]=v.x; r[4*i+1]=v.y; r[4*i+2]=v.z; r[4*i+3]=v.w; }
}

__device__ __forceinline__ u32 pkbf(float a, float b){
  u32 ua=__float_as_uint(a); ua=(ua+0x7FFFu+((ua>>16)&1u))>>16;
  u32 ub=__float_as_uint(b); ub=(ub+0x7FFFu+((ub>>16)&1u))>>16;
  return ua | (ub<<16);
}

__global__ void k_prep(const float* __restrict__ rela, const float* __restrict__ w1,
                       const float* __restrict__ wp, const float* __restrict__ wn,
                       const float* __restrict__ wf,
                       float* __restrict__ W3, float* __restrict__ AR, float* __restrict__ AQ,
                       int nrel){
  int t = blockIdx.x*blockDim.x + threadIdx.x;
  if (t < 3*DD*DD){
    int s = t/(DD*DD), idx = t%(DD*DD);
    W3[t] = (s==0)?wp[idx]:((s==1)?wn[idx]:wf[idx]);
  }
  if (t < nrel*HID){
    int r=t/HID, j=t-r*HID;
    float sr=0.f, sq=0.f;
#pragma unroll
    for (int k=0;k<DD;k++){
      float e = rela[r*DD+k];
      sr += e*w1[j*3*DD + DD + k];
      sq += e*w1[j*3*DD + 2*DD + k];
    }
    AR[r*32+j]=sr; AQ[r*32+j]=sq;
  }
}

__global__ void k_rwtw(const float* __restrict__ rela, const float* __restrict__ timee,
                       const float* __restrict__ W3,
                       float* __restrict__ RW, float* __restrict__ TW,
                       int nrel, int ntime){
  int t = blockIdx.x*blockDim.x+threadIdx.x;
  int totR = 3*nrel*DD, totT = 3*ntime*DD;
  if (t < totR){
    int sel = t/(nrel*DD); int rem = t - sel*nrel*DD; int r = rem/DD; int i = rem - r*DD;
    const float* w = W3 + sel*DD*DD + i*DD;
    const float* e = rela + (size_t)r*DD;
    float s=0.f;
#pragma unroll
    for (int k=0;k<DD;k++) s += e[k]*w[k];
    RW[t]=s;
  }
  if (t < totT){
    int sel = t/(ntime*DD); int rem = t - sel*ntime*DD; int tt = rem/DD; int i = rem - tt*DD;
    const float* w = W3 + sel*DD*DD + i*DD;
    const float* e = timee + (size_t)tt*DD;
    float s=0.f;
#pragma unroll
    for (int k=0;k<DD;k++) s += e[k]*w[k];
    TW[t]=s;
  }
}

// f32 RT (fallback path only)
__global__ void k_rt(const float* __restrict__ rela, const float* __restrict__ timee,
                     const float* __restrict__ W3, float* __restrict__ RT,
                     int nrel, int ntime){
  int row = blockIdx.x*blockDim.x+threadIdx.x;
  int tot = 3*nrel*ntime;
  if (row>=tot) return;
  int per = nrel*ntime;
  int sel = row/per; int rem = row - sel*per; int r = rem/ntime; int t = rem - r*ntime;
  float e[DD], tv[DD];
  load20(rela + (size_t)r*DD, e);
  load20(timee + (size_t)t*DD, tv);
#pragma unroll
  for (int k=0;k<DD;k++) e[k]+=tv[k];
  const float* W = W3 + sel*DD*DD;
  float o[DD];
#pragma unroll
  for (int i=0;i<DD;i++){
    const float4* wr = (const float4*)(W + i*DD);
    float s=0.f;
#pragma unroll
    for (int c=0;c<5;c++){ float4 w=wr[c]; s += e[4*c]*w.x + e[4*c+1]*w.y + e[4*c+2]*w.z + e[4*c+3]*w.w; }
    o[i]=s;
  }
  float4* op=(float4*)(RT + (size_t)row*DD);
#pragma unroll
  for (int c=0;c<5;c++){ float4 v; v.x=o[4*c]; v.y=o[4*c+1]; v.z=o[4*c+2]; v.w=o[4*c+3]; op[c]=v; }
}

// ---- F0: zero d_out/bufF (even blocks) || hist layers 0+1 (odd) ----
__global__ void __launch_bounds__(256) k_pre(const int* __restrict__ dst, int* __restrict__ cnt,
        int* __restrict__ rank, int E, int N,
        float4* __restrict__ dout4, size_t nd4,
        float4* __restrict__ bF, size_t nf4){
  int g=blockIdx.x, tid=threadIdx.x;
  int half=gridDim.x>>1;
  if (g & 1){
    int stride=half*256;
    int E2=2*E;
    for (int e=(g>>1)*256+tid; e<E2; e+=stride){
      int l=(e>=E)?1:0;
      rank[e]=atomicAdd(&cnt[(size_t)l*N+dst[e]],1);
    }
  } else {
    float4 z=make_float4(0.f,0.f,0.f,0.f);
    size_t i=(size_t)(g>>1)*256+tid, st=(size_t)half*256;
    for (size_t k=i;k<nd4;k+=st) dout4[k]=z;
    for (size_t k=i;k<nf4;k+=st) bF[k]=z;
  }
}

// ---- scans (M elements), exclusive; scan_write adds `base` and handles deg-0 rows ----
__global__ void k_scan_part(const int* __restrict__ cnt, int* __restrict__ part, int M, int C){
  __shared__ int sm[256];
  int b=blockIdx.x, t=threadIdx.x;
  int lo=b*C, hi=lo+C; if (hi>M) hi=M; if (lo>M) lo=M;
  int s=0;
  for (int i=lo+t; i<hi; i+=256) s+=cnt[i];
  sm[t]=s; __syncthreads();
  for (int o=128;o>0;o>>=1){ if (t<o) sm[t]+=sm[t+o]; __syncthreads(); }
  if (t==0) part[b]=sm[0];
}

__global__ void k_scan_top(int* __restrict__ part, int* __restrict__ listc){
  __shared__ int sm[NB_SCAN];
  int t=threadIdx.x;
  if (t==0){ listc[0]=0; listc[1]=0; listc[2]=0; listc[3]=0; }
  int v=part[t]; sm[t]=v; __syncthreads();
  for (int o=1;o<NB_SCAN;o<<=1){
    int u=(t>=o)?sm[t-o]:0; __syncthreads();
    sm[t]+=u; __syncthreads();
  }
  part[t]=sm[t]-v;   // exclusive
}

// ZM=1: zero f16 rows of zb0 (i<Nsplit) / zb1 (i>=Nsplit) when cnt==0.
// ZM=2: write bcls into d_out slot of node i when cnt==0 (deg-0 final nodes).
template<int ZM>
__global__ void k_scan_write(const int* __restrict__ cnt, const int* __restrict__ part,
                             int* __restrict__ rowptr, int M, int C, int base,
                             u16* __restrict__ zb0, u16* __restrict__ zb1, int Nsplit,
                             const int* __restrict__ nb, const int* __restrict__ ne,
                             const int* __restrict__ nentp, const float* __restrict__ bcls,
                             float* __restrict__ dout){
  __shared__ int sm[256];
  int b=blockIdx.x, t=threadIdx.x;
  int lo=b*C, hi=lo+C; if (hi>M) hi=M; if (lo>M) lo=M;
  int run=part[b]+base;
  for (int bb=lo; bb<hi; bb+=256){
    int i=bb+t;
    int v=(i<hi)?cnt[i]:0;
    if (i<hi && v==0){
      if (ZM==1){
        u16* o=(i<Nsplit)? zb0+(size_t)i*HROW : zb1+(size_t)(i-Nsplit)*HROW;
        uint4 z=make_uint4(0u,0u,0u,0u);
        uint4* o4=(uint4*)o;
        o4[0]=z; o4[1]=z; *((uint2*)(o4+2))=make_uint2(0u,0u);
      } else if (ZM==2){
        long long stride=nentp[0];
        dout[(long long)nb[i]*stride + ne[i]] = bcls[0];
      }
    }
    sm[t]=v; __syncthreads();
    for (int o=1;o<256;o<<=1){
      int u=(t>=o)?sm[t-o]:0; __syncthreads();
      sm[t]+=u; __syncthreads();
    }
    if (i<hi) rowptr[i]=run+sm[t]-v;
    int tot=sm[255];
    __syncthreads();
    run+=tot;
  }
  if (hi==M && t==0) rowptr[M]=run;
}

// ---- scatter layers 0+1 together (global CSR positions) ----
__global__ void __launch_bounds__(256) k_scat01(const int* __restrict__ src,const int* __restrict__ dst,
  const int* __restrict__ rel,const int* __restrict__ qrel,const int* __restrict__ rtm,
  const int* __restrict__ rank,const int* __restrict__ rowptr,int4* __restrict__ recs,int E,int N){
  int e=blockIdx.x*blockDim.x+threadIdx.x;
  if (e>=2*E) return;
  int l=(e>=E)?1:0;
  int d=dst[e];
  int pos=rowptr[(size_t)l*N+d]+rank[e];
  recs[pos]=make_int4(src[e], rel[e]|(qrel[e]<<16), rtm[e], d);
}

// ---- scatter layer 2 (rowptr2 already carries +2E base) ----
__global__ void __launch_bounds__(256) k_scat2(const int* __restrict__ src,const int* __restrict__ dst,
  const int* __restrict__ rel,const int* __restrict__ qrel,const int* __restrict__ rtm,
  const int* __restrict__ rank,const int* __restrict__ rowptr2,int4* __restrict__ recs,int E){
  int e=blockIdx.x*blockDim.x+threadIdx.x;
  if (e>=E) return;
  int d=dst[e];
  int pos=rowptr2[d]+rank[e];
  recs[pos]=make_int4(src[e], rel[e]|(qrel[e]<<16), rtm[e], d);
}

// ---- fused layer: f16 hidden (leaky pre-applied, 64B rows, packed dots), streamed z,
//      RW/TW transform, bf16-packed LDS segmented reduce. HIST: 1/3 blocks do l2 hist.
//      FINAL: head writes bcls+leakydot directly to d_out; crossings -> bufF + list. ----
template<bool HASH,bool FINAL,bool HIST>
__global__ void __launch_bounds__(256) k_fused(
    const int4* __restrict__ recs,
    const u16* __restrict__ hin, u16* __restrict__ hout, float* __restrict__ bufF,
    const float* __restrict__ RW, const float* __restrict__ TW,
    const float* __restrict__ AR, const float* __restrict__ AQ,
    const float* __restrict__ w1, const float* __restrict__ w2, const float* __restrict__ W3,
    int E, int nrel, int ntime,
    const int* __restrict__ hB_dst, int* __restrict__ hB_cnt, int* __restrict__ hB_rank, int hB_E,
    const float* __restrict__ wcls, const float* __restrict__ bcls,
    const int* __restrict__ nbv, const int* __restrict__ nev, const int* __restrict__ nentp,
    float* __restrict__ outp,
    int* __restrict__ list, int* __restrict__ listc)
{
  int lb;
  if (HIST){
    int g=blockIdx.x;
    int r3=g%3, b3=g/3;
    if (r3==2){
      int H=gridDim.x/3;
      int stride=H*256;
      for (int e=b3*256+threadIdx.x; e<hB_E; e+=stride)
        hB_rank[e]=atomicAdd(&hB_cnt[hB_dst[e]],1);
      return;
    }
    lb=b3*2+r3;
  } else lb=blockIdx.x;
  int bstart=lb*256;
  if (bstart>=E) return;

  __shared__ u32   sW1hp[HID*10];
  __shared__ u32   sW3p[3*DD*10];
  __shared__ float sW2[32];
  __shared__ u32   smsg[256*10];
  __shared__ int   sdst[256];
  __shared__ int   s_prevdst, s_nextdst;
  if (HASH){
    for (int t=threadIdx.x; t<HID*10; t+=blockDim.x){
      int j=t/10, c=t-j*10;
      sW1hp[t]=pkhf(w1[j*3*DD+2*c], w1[j*3*DD+2*c+1]);
    }
    for (int t=threadIdx.x; t<3*DD*10; t+=blockDim.x){
      int i=t/10, c=t-i*10;
      sW3p[t]=pkhf(W3[i*DD+2*c], W3[i*DD+2*c+1]);
    }
  }
  if (threadIdx.x<HID) sW2[threadIdx.x]=w2[threadIdx.x];

  int tid = threadIdx.x;
  int bsize = E - bstart; if (bsize>256) bsize=256;
  int j = bstart + tid;
  bool active = (tid < bsize);

  if (tid==0){
    s_prevdst = (bstart>0) ? recs[-1 + (ptrdiff_t)bstart].w : -1;
    s_nextdst = (bstart+bsize < E) ? recs[bstart+bsize].w : -1;
  }
  __syncthreads();

  int dstv = -1;
  float m[DD];
  if (active){
    int4 rc = recs[j];
    int s = rc.x;
    int r = rc.y & 0xFFFF;
    int q = ((unsigned)rc.y) >> 16;
    int t = rc.z;
    dstv  = rc.w;
    int sel = (t>0)?2:((t==0)?1:0);
    int ta = (t<0)?-t:t;

    u32 hh[10];
    if (HASH){
      const uint4* hp=(const uint4*)(hin+(size_t)s*HROW);
      uint4 A=hp[0], B=hp[1]; uint2 Cc=*((const uint2*)(hp+2));
      hh[0]=A.x; hh[1]=A.y; hh[2]=A.z; hh[3]=A.w;
      hh[4]=B.x; hh[5]=B.y; hh[6]=B.z; hh[7]=B.w;
      hh[8]=Cc.x; hh[9]=Cc.y;
    }

    float z=0.f;
    {
      const float4* ap=(const float4*)(AR+(size_t)r*32);
      const float4* qp=(const float4*)(AQ+(size_t)q*32);
#pragma unroll
      for (int c=0;c<7;c++){
        float4 x=ap[c], y=qp[c];
        float s4[4]={x.x+y.x, x.y+y.y, x.z+y.z, x.w+y.w};
#pragma unroll
        for (int u=0;u<4;u++){
          int jj=4*c+u;
          float sum=s4[u];
          if (HASH) sum = dot10p(hh, &sW1hp[jj*10], sum);
          z += fmaxf(sum,0.f)*sW2[jj];
        }
      }
      float2 x2=*(const float2*)(AR+(size_t)r*32+28);
      float2 y2=*(const float2*)(AQ+(size_t)q*32+28);
      float s0=x2.x+y2.x, s1=x2.y+y2.y;
      if (HASH){
        s0 = dot10p(hh, &sW1hp[28*10], s0);
        s1 = dot10p(hh, &sW1hp[29*10], s1);
      }
      z += fmaxf(s0,0.f)*sW2[28] + fmaxf(s1,0.f)*sW2[29];
    }
    float score = 1.f/(1.f+__expf(-z));

    const float4* rwp=(const float4*)(RW + ((size_t)(sel*nrel+r))*DD);
    const float4* twp=(const float4*)(TW + ((size_t)(sel*ntime+ta))*DD);
#pragma unroll
    for (int c=0;c<5;c++){
      float4 a4=rwp[c], b4=twp[c];
      float mv[4]={a4.x+b4.x, a4.y+b4.y, a4.z+b4.z, a4.w+b4.w};
      if (HASH){
#pragma unroll
        for (int u=0;u<4;u++)
          mv[u] = dot10p(hh, &sW3p[(sel*DD+4*c+u)*10], mv[u]);
      }
#pragma unroll
      for (int u=0;u<4;u++) m[4*c+u]=score*mv[u];
      smsg[tid*10+2*c]  =pkbf(m[4*c+0],m[4*c+1]);
      smsg[tid*10+2*c+1]=pkbf(m[4*c+2],m[4*c+3]);
    }
  }
  sdst[tid] = active ? dstv : -2;
  __syncthreads();

  if (!active) return;
  bool isHead = (tid==0) ? (s_prevdst != dstv) : (sdst[tid-1] != dstv);
  if (!(isHead || tid==0)) return;
  int k=tid+1;
  for (; k<bsize && sdst[k]==dstv; ++k){
    const u32* row=&smsg[k*10];
#pragma unroll
    for (int i2=0;i2<10;i2++){
      u32 w=row[i2];
      m[2*i2]  +=__uint_as_float(w<<16);
      m[2*i2+1]+=__uint_as_float(w&0xFFFF0000u);
    }
  }
  bool crossStart = (tid==0 && !isHead);
  bool crossEnd   = (k==bsize) && (s_nextdst==dstv);
  if (crossStart || crossEnd){
    float* o = bufF + (size_t)dstv*DD;
#pragma unroll
    for (int i=0;i<DD;i++) atomicAdd(o+i, m[i]);
    if (isHead){
      int p = atomicAdd(listc,1);
      list[p] = dstv;
    }
  } else {
    if (!FINAL){
      u32 o10[10];
#pragma unroll
      for (int i2=0;i2<10;i2++){
        float x0=m[2*i2], x1=m[2*i2+1];
        x0=fmaxf(x0,0.01f*x0); x1=fmaxf(x1,0.01f*x1);
        o10[i2]=pkhf(x0,x1);
      }
      uint4* hp=(uint4*)(hout+(size_t)dstv*HROW);
      hp[0]=make_uint4(o10[0],o10[1],o10[2],o10[3]);
      hp[1]=make_uint4(o10[4],o10[5],o10[6],o10[7]);
      *((uint2*)(hp+2))=make_uint2(o10[8],o10[9]);
    } else {
      float rsum=bcls[0];
#pragma unroll
      for (int i=0;i<DD;i++){ float x=fmaxf(m[i],0.01f*m[i]); rsum += x*wcls[i]; }
      long long stride = nentp[0];
      outp[(long long)nbv[dstv]*stride + nev[dstv]] = rsum;
    }
  }
}

// ---- finish crossing segments: FINAL -> d_out (bcls + leakydot); else f16 hout + re-zero ----
template<bool FINAL>
__global__ void __launch_bounds__(256) k_fixup(float* __restrict__ bufF, u16* __restrict__ hout,
   const float* __restrict__ wcls, const float* __restrict__ bcls,
   const int* __restrict__ nb, const int* __restrict__ ne, const int* __restrict__ nentp,
   float* __restrict__ out,
   const int* __restrict__ list, const int* __restrict__ listc){
  int c=*listc;
  for (int i=blockIdx.x*blockDim.x+threadIdx.x; i<c; i+=gridDim.x*blockDim.x){
    int n=list[i];
    float* p=bufF+(size_t)n*DD;
    if (FINAL){
      float rsum=bcls[0];
#pragma unroll
      for (int jj=0;jj<DD;jj++){ float v=p[jj]; float x=fmaxf(v,0.01f*v); rsum+=x*wcls[jj]; }
      long long stride=nentp[0];
      out[(long long)nb[n]*stride+ne[n]]=rsum;
    } else {
      float v[DD];
#pragma unroll
      for (int jj=0;jj<DD;jj++){ v[jj]=p[jj]; p[jj]=0.f; }
      u32 o10[10];
#pragma unroll
      for (int i2=0;i2<10;i2++){
        float x0=v[2*i2], x1=v[2*i2+1];
        x0=fmaxf(x0,0.01f*x0); x1=fmaxf(x1,0.01f*x1);
        o10[i2]=pkhf(x0,x1);
      }
      uint4* hp=(uint4*)(hout+(size_t)n*HROW);
      hp[0]=make_uint4(o10[0],o10[1],o10[2],o10[3]);
      hp[1]=make_uint4(o10[4],o10[5],o10[6],o10[7]);
      *((uint2*)(hp+2))=make_uint2(o10[8],o10[9]);
    }
  }
}

// ================= fallback (round-2 proven atomic path, f32) =================
template<bool HASH>
__global__ void __launch_bounds__(256) k_edge(
    const int* __restrict__ src, const int* __restrict__ dst,
    const int* __restrict__ rel, const int* __restrict__ qrel,
    const int* __restrict__ rtm,
    const float* __restrict__ hin, float* __restrict__ hout,
    const float* __restrict__ RT, const float* __restrict__ AR, const float* __restrict__ AQ,
    const float* __restrict__ w1, const float* __restrict__ w2, const float* __restrict__ W3,
    int E, int nrel, int ntime)
{
  __shared__ float sW1h[HID*DD];
  __shared__ float sW2[32];
  __shared__ float sW3[3*DD*DD];
  for (int t=threadIdx.x; t<HID*DD; t+=blockDim.x){ int j=t/DD,k=t-j*DD; sW1h[t]=w1[j*3*DD+k]; }
  if (threadIdx.x<HID) sW2[threadIdx.x]=w2[threadIdx.x];
  for (int t=threadIdx.x; t<3*DD*DD; t+=blockDim.x) sW3[t]=W3[t];
  __syncthreads();
  int e = blockIdx.x*blockDim.x+threadIdx.x;
  if (e>=E) return;
  int s=src[e], d=dst[e], r=rel[e], q=qrel[e], t=rtm[e];
  int sel = (t>0)?2:((t==0)?1:0);
  int ta = (t<0)?-t:t;
  float h[DD];
  if (HASH){
    load20(hin+(size_t)s*DD, h);
#pragma unroll
    for (int i=0;i<DD;i++) h[i]=fmaxf(h[i],0.01f*h[i]);
  }
  float a[HID];
  {
    const float4* ap=(const float4*)(AR+(size_t)r*32);
    const float4* qp=(const float4*)(AQ+(size_t)q*32);
#pragma unroll
    for (int c=0;c<7;c++){
      float4 x=ap[c], y=qp[c];
      a[4*c+0]=x.x+y.x; a[4*c+1]=x.y+y.y; a[4*c+2]=x.z+y.z; a[4*c+3]=x.w+y.w;
    }
    float2 x=*(const float2*)(AR+(size_t)r*32+28);
    float2 y=*(const float2*)(AQ+(size_t)q*32+28);
    a[28]=x.x+y.x; a[29]=x.y+y.y;
  }
  if (HASH){
#pragma unroll
    for (int j=0;j<HID;j++){
      const float4* wr=(const float4*)&sW1h[j*DD];
      float sum=a[j];
#pragma unroll
      for (int c=0;c<5;c++){ float4 w=wr[c]; sum += h[4*c]*w.x+h[4*c+1]*w.y+h[4*c+2]*w.z+h[4*c+3]*w.w; }
      a[j]=sum;
    }
  }
  float z=0.f;
#pragma unroll
  for (int j=0;j<HID;j++) z += fmaxf(a[j],0.f)*sW2[j];
  float score = 1.f/(1.f+__expf(-z));
  float tr[DD];
  load20(RT + ((size_t)(sel*nrel+r)*ntime + ta)*DD, tr);
  if (HASH){
    const float* Ws = sW3 + sel*DD*DD;
#pragma unroll
    for (int i=0;i<DD;i++){
      const float4* wr=(const float4*)(Ws+i*DD);
      float sum=tr[i];
#pragma unroll
      for (int c=0;c<5;c++){ float4 w=wr[c]; sum += h[4*c]*w.x+h[4*c+1]*w.y+h[4*c+2]*w.z+h[4*c+3]*w.w; }
      tr[i]=sum;
    }
  }
  float* o = hout + (size_t)d*DD;
#pragma unroll
  for (int i=0;i<DD;i++) atomicAdd(o+i, score*tr[i]);
}

__global__ void k_result(const float* __restrict__ h, const float* __restrict__ wcls,
                         const float* __restrict__ bcls, float* __restrict__ res, int N){
  int i = blockIdx.x*blockDim.x+threadIdx.x;
  if (i>=N) return;
  float acc = bcls[0];
  const float4* q=(const float4*)(h+(size_t)i*DD);
#pragma unroll
  for (int c=0;c<5;c++){
    float4 v=q[c];
    float x0=fmaxf(v.x,0.01f*v.x), x1=fmaxf(v.y,0.01f*v.y);
    float x2=fmaxf(v.z,0.01f*v.z), x3=fmaxf(v.w,0.01f*v.w);
    acc += x0*wcls[4*c]+x1*wcls[4*c+1]+x2*wcls[4*c+2]+x3*wcls[4*c+3];
  }
  res[i]=acc;
}

__global__ void k_scatter(const float* __restrict__ res, const int* __restrict__ nb,
                          const int* __restrict__ ne, const int* __restrict__ nentp,
                          float* __restrict__ out, int N){
  int i=blockIdx.x*blockDim.x+threadIdx.x;
  if (i>=N) return;
  long long stride = nentp[0];
  out[(long long)nb[i]*stride + ne[i]] = res[i];
}

extern "C" void kernel_launch(void* const* d_in, const int* in_sizes, int n_in,
                              void* d_out, int out_size, void* d_ws, size_t ws_size,
                              hipStream_t stream){
  const int*   src =(const int*)d_in[0];
  const int*   dst =(const int*)d_in[1];
  const int*   rel =(const int*)d_in[2];
  const int*   qrel=(const int*)d_in[3];
  const int*   rtm =(const int*)d_in[4];
  const int*   nb  =(const int*)d_in[5];
  const int*   ne  =(const int*)d_in[6];
  const float* rela=(const float*)d_in[7];
  const float* timee=(const float*)d_in[8];
  const float* w1  =(const float*)d_in[9];
  const float* w2  =(const float*)d_in[10];
  const float* wp  =(const float*)d_in[11];
  const float* wn  =(const float*)d_in[12];
  const float* wf  =(const float*)d_in[13];
  const float* wcls=(const float*)d_in[14];
  const float* bcls=(const float*)d_in[15];
  const int*   nentp=(const int*)d_in[17];

  const int Lc=3;
  int LE=in_sizes[0]; int E=LE/Lc;
  int N=in_sizes[5];
  int nrel=in_sizes[7]/DD;
  int ntime=in_sizes[8]/DD;

  auto al=[](size_t x){ return (x+(size_t)255)&~(size_t)255; };
  size_t szBufH=al((size_t)N*HROW*2);
  size_t szBuf =al((size_t)N*DD*4);
  size_t szRW  =al((size_t)3*nrel*DD*4);
  size_t szTW  =al((size_t)3*ntime*DD*4);
  size_t szRTf =al((size_t)3*nrel*ntime*DD*4);
  size_t szA   =al((size_t)nrel*32*4);
  size_t szW3  =al((size_t)3*DD*DD*4);
  size_t szRow =al(((size_t)3*N+3)*4);
  size_t szRank=al((size_t)LE*4);
  size_t szCnt =al((size_t)Lc*N*4);
  size_t szRecs=al((size_t)LE*16);
  size_t szPart=al((size_t)NB_SCAN*4);
  size_t szList=al((size_t)(131072+16)*4);
  size_t need = 2*szBufH+szBuf+szRW+szTW+2*szA+szW3+szRow+szRank+szCnt+szRecs+szPart+szList;

  dim3 blk(256);
  int prepTot = (3*DD*DD > nrel*HID) ? 3*DD*DD : nrel*HID;
  int rtTot=3*nrel*ntime;
  int rwtwTot = 3*ntime*DD;

  if (ws_size >= need){
    char* base=(char*)d_ws;
    size_t off=0;
    u16*   b0 =(u16*)(base+off);    off+=szBufH;
    u16*   b1 =(u16*)(base+off);    off+=szBufH;
    float* bufF=(float*)(base+off); off+=szBuf;
    float* RW  =(float*)(base+off); off+=szRW;
    float* TW  =(float*)(base+off); off+=szTW;
    float* AR  =(float*)(base+off); off+=szA;
    float* AQ  =(float*)(base+off); off+=szA;
    float* W3  =(float*)(base+off); off+=szW3;
    int*   rowptr=(int*)(base+off); off+=szRow;
    int*   rowptr2=rowptr+(size_t)2*N+1;
    int*   rank=(int*)(base+off);  off+=szRank;
    int*   cnt =(int*)(base+off);  off+=szCnt;
    int4*  recs=(int4*)(base+off); off+=szRecs;
    int*   part=(int*)(base+off);  off+=szPart;
    int*   listc=(int*)(base+off);
    int*   list =listc+16;          off+=szList;

    float* dout=(float*)d_out;

    (void)hipMemsetAsync(cnt,0,(size_t)Lc*N*4,stream);
    k_prep<<<dim3((prepTot+255)/256),blk,0,stream>>>(rela,w1,wp,wn,wf,W3,AR,AQ,nrel);
    k_rwtw<<<dim3((rwtwTot+255)/256),blk,0,stream>>>(rela,timee,W3,RW,TW,nrel,ntime);

    size_t nd4=(size_t)out_size>>2;
    size_t nb4=(size_t)N*DD/4;
    k_pre<<<dim3(8192),blk,0,stream>>>(dst,cnt,rank,E,N,(float4*)dout,nd4,
                                       (float4*)bufF,nb4);

    int LB=(E+255)/256;
    int H=(LB+1)/2;

    // scan layers 0+1 over 2N (zero deg-0 rows of b0/b1; resets listc[0..3])
    {
      int M=2*N, C=(M+NB_SCAN-1)/NB_SCAN;
      k_scan_part<<<dim3(NB_SCAN),blk,0,stream>>>(cnt,part,M,C);
      k_scan_top<<<dim3(1),dim3(NB_SCAN),0,stream>>>(part,listc);
      k_scan_write<1><<<dim3(NB_SCAN),blk,0,stream>>>(cnt,part,rowptr,M,C,0,
          b0,b1,N, nullptr,nullptr,nullptr,nullptr,nullptr);
    }
    k_scat01<<<dim3((2*E+255)/256),blk,0,stream>>>(src,dst,rel,qrel,rtm,rank,rowptr,recs,E,N);

    // fused layer 0 (no hidden): compute || hist(l2); lists into slot 0
    k_fused<false,false,true><<<dim3(3*H),blk,0,stream>>>(recs,nullptr,b0,bufF,
        RW,TW,AR,AQ,w1,w2,W3,E,nrel,ntime,
        dst+(size_t)2*E,cnt+(size_t)2*N,rank+(size_t)2*E,E,
        wcls,bcls,nb,ne,nentp,dout,
        list,listc);
    k_fixup<false><<<dim3(128),blk,0,stream>>>(bufF,b0,wcls,bcls,nb,ne,nentp,dout,list,listc);

    // scan layer 2 (base 2E; deg-0 nodes get bcls written to d_out; resets listc[0..3])
    {
      int C=(N+NB_SCAN-1)/NB_SCAN;
      k_scan_part<<<dim3(NB_SCAN),blk,0,stream>>>(cnt+(size_t)2*N,part,N,C);
      k_scan_top<<<dim3(1),dim3(NB_SCAN),0,stream>>>(part,listc);
      k_scan_write<2><<<dim3(NB_SCAN),blk,0,stream>>>(cnt+(size_t)2*N,part,rowptr2,N,C,2*E,
          nullptr,nullptr,0, nb,ne,nentp,bcls,dout);
    }
    k_scat2<<<dim3(LB),blk,0,stream>>>(src+(size_t)2*E,dst+(size_t)2*E,rel+(size_t)2*E,
        qrel+(size_t)2*E,rtm+(size_t)2*E,rank+(size_t)2*E,rowptr2,recs,E);

    // fused layer 1; lists into slot 1
    k_fused<true,false,false><<<dim3(LB),blk,0,stream>>>(recs+(size_t)E,b0,b1,bufF,
        RW,TW,AR,AQ,w1,w2,W3,E,nrel,ntime,
        nullptr,nullptr,nullptr,0,
        wcls,bcls,nb,ne,nentp,dout,
        list+32768,listc+1);
    k_fixup<false><<<dim3(128),blk,0,stream>>>(bufF,b1,wcls,bcls,nb,ne,nentp,dout,list+32768,listc+1);

    // fused layer 2 (FINAL): heads write d_out directly; crossings -> bufF + slot 2
    k_fused<true,true,false><<<dim3(LB),blk,0,stream>>>(recs+(size_t)2*E,b1,nullptr,bufF,
        RW,TW,AR,AQ,w1,w2,W3,E,nrel,ntime,
        nullptr,nullptr,nullptr,0,
        wcls,bcls,nb,ne,nentp,dout,
        list+65536,listc+2);
    k_fixup<true><<<dim3(128),blk,0,stream>>>(bufF,nullptr,wcls,bcls,nb,ne,nentp,dout,list+65536,listc+2);
  } else {
    // fallback: proven round-2 atomic path (scratch carved from d_out, res in ws)
    char* base=(char*)d_out; float* res=(float*)d_ws;
    size_t off=0;
    float* buf0=(float*)(base+off); off+=szBuf;
    float* buf1=(float*)(base+off); off+=szBuf;
    float* RT  =(float*)(base+off); off+=szRTf;
    float* AR  =(float*)(base+off); off+=szA;
    float* AQ  =(float*)(base+off); off+=szA;
    float* W3  =(float*)(base+off); off+=szW3;
    k_prep<<<dim3((prepTot+255)/256),blk,0,stream>>>(rela,w1,wp,wn,wf,W3,AR,AQ,nrel);
    k_rt<<<dim3((rtTot+255)/256),blk,0,stream>>>(rela,timee,W3,RT,nrel,ntime);
    dim3 egrid((E+255)/256);
    dim3 ngrid((N+255)/256);
    (void)hipMemsetAsync(buf0,0,(size_t)N*DD*4,stream);
    k_edge<false><<<egrid,blk,0,stream>>>(src,dst,rel,qrel,rtm,nullptr,buf0,RT,AR,AQ,w1,w2,W3,E,nrel,ntime);
    (void)hipMemsetAsync(buf1,0,(size_t)N*DD*4,stream);
    k_edge<true><<<egrid,blk,0,stream>>>(src+(size_t)E,dst+(size_t)E,rel+(size_t)E,qrel+(size_t)E,rtm+(size_t)E,
                                         buf0,buf1,RT,AR,AQ,w1,w2,W3,E,nrel,ntime);
    (void)hipMemsetAsync(buf0,0,(size_t)N*DD*4,stream);
    k_edge<true><<<egrid,blk,0,stream>>>(src+(size_t)2*E,dst+(size_t)2*E,rel+(size_t)2*E,qrel+(size_t)2*E,rtm+(size_t)2*E,
                                         buf1,buf0,RT,AR,AQ,w1,w2,W3,E,nrel,ntime);
    k_result<<<ngrid,blk,0,stream>>>(buf0,wcls,bcls,res,N);
    (void)hipMemsetAsync(d_out,0,(size_t)out_size*sizeof(float),stream);
    k_scatter<<<ngrid,blk,0,stream>>>(res,nb,ne,nentp,(float*)d_out,N);
  }
}